// Round 2
// baseline (176.225 us; speedup 1.0000x reference)
//
#include <hip/hip_runtime.h>

// Problem constants (from reference setup_inputs) — all tensors are fp32.
#define BATCH 16
#define NVEC 1024
#define NDIM 64
#define NHID 32
#define NW   10
#define NCLS 10
#define NOFF 11      // diag + 10 power-of-2 offsets (chord mask: 11 nnz/row)
#define WPAD 12      // padded weights-per-row so k_chain reads 3x float4
#define NCHUNK (NDIM / 4)   // 16 d-chunks in k_chain
#define W2PAD 36     // padded row length for the 64-row LDS W2 cache

// ---------------------------------------------------------------------------
// Kernel 1 (fused transpose + weights): all sparse chord weights, all 10
// layers. Block = (layer i, 8 rows, ALL 16 b). Thread = (b = t&15,
// jq = (t>>4)&3, nl = t>>6) computing 2 rows x 8 hidden -> h[2][8].
//
//  * Each block needs exactly 64 W2T rows
//    (k in [0,24) u ({32,64,128,256,512}+[0,8)) relative to nbase), staged
//    into LDS directly from fW2 (8 scalar loads/thread, 32B-coalesced) —
//    the separate transpose kernel is gone.
//  * Row weights accumulate in a 6 KB LDS buffer and are written out as
//    384 coalesced float4 per block (previously 22 predicated scalar
//    stores/thread at 48B/12KB strides, ~16 L2 sectors each).
//  * Block (0,0) zeroes the chain-completion counters (stream order makes
//    the zero visible to k_chain).
// grid (NVEC/8, NW), block 256.
// ---------------------------------------------------------------------------
__global__ __launch_bounds__(256) void k_weights(
    const float* __restrict__ data,   // [B][NVEC][NDIM]
    const float* __restrict__ fW1,    // [NW][NDIM][NHID]
    const float* __restrict__ fb1,    // [NW][NHID]
    const float* __restrict__ fW2,    // [NW][NHID][NVEC]
    const float* __restrict__ fb2,    // [NW][NVEC]
    float* __restrict__ Wsp,          // [NW][B][NVEC][WPAD]
    int* __restrict__ cnt)            // [BATCH] chain completion counters
{
    const int i = blockIdx.y;
    const int nbase = blockIdx.x * 8;
    const int t = threadIdx.x;
    const int b  = t & 15;
    const int jq = (t >> 4) & 3;
    const int nl = t >> 6;            // wave index; lane = b + 16*jq
    const int j0 = jq * 8;

    __shared__ __align__(16) float sW1[NDIM * NHID];   // [d][j], 8 KB
    __shared__ float sb1[NHID];
    __shared__ __align__(16) float sW2r[64 * W2PAD];   // 64 gather rows, 9 KB
    __shared__ float sb2[64];                          // fb2 at those rows
    __shared__ __align__(16) float rws[128 * WPAD];    // row weights, 6 KB

    if (blockIdx.x == 0 && i == 0 && t < BATCH) cnt[t] = 0;

    {
        const float4* w1v = (const float4*)(fW1 + (size_t)i * NDIM * NHID);
        float4* s4 = (float4*)sW1;
        #pragma unroll
        for (int k = t; k < NDIM * NHID / 4; k += 256) s4[k] = w1v[k];
        if (t < NHID) sb1[t] = fb1[i * NHID + t];

        // stage the 64 needed fW2 columns (rows of W2^T) into LDS
        const int j  = t >> 3;
        const int s0 = t & 7;
        const float* w2 = fW2 + ((size_t)i * NHID + j) * NVEC;
        #pragma unroll
        for (int c = 0; c < 8; ++c) {
            int s = s0 + c * 8;
            int k = (s < 24) ? s : ((32 << ((s - 24) >> 3)) + ((s - 24) & 7));
            int m = (nbase + k) & (NVEC - 1);
            sW2r[s * W2PAD + j] = w2[m];               // 8-lane 32B segments
        }
        if (t < 64) {
            int s = t;
            int k = (s < 24) ? s : ((32 << ((s - 24) >> 3)) + ((s - 24) & 7));
            int m = (nbase + k) & (NVEC - 1);
            sb2[s] = fb2[(size_t)i * NVEC + m];
        }
        // zero the WPAD pad slot so Wsp never carries stale-LDS bits
        for (int k = t; k < 128; k += 256) rws[k * WPAD + (WPAD - 1)] = 0.0f;
    }
    __syncthreads();

    float h[2][8];
    #pragma unroll
    for (int r = 0; r < 2; ++r)
        #pragma unroll
        for (int jj = 0; jj < 8; ++jj) h[r][jj] = sb1[j0 + jj];

    const int n0 = nbase + nl * 2;
    const float4* arow0 = (const float4*)(data + ((size_t)(b * NVEC) + n0) * NDIM);
    const float4* arow1 = (const float4*)(data + ((size_t)(b * NVEC) + n0 + 1) * NDIM);

    #pragma unroll 4
    for (int g = 0; g < 16; ++g) {       // 4 d-dims per iteration
        float4 a0 = arow0[g];
        float4 a1 = arow1[g];
        float as0[4] = {a0.x, a0.y, a0.z, a0.w};
        float as1[4] = {a1.x, a1.y, a1.z, a1.w};
        #pragma unroll
        for (int dk = 0; dk < 4; ++dk) {
            const float4* wp = (const float4*)(&sW1[(g * 4 + dk) * NHID + j0]);
            float4 w0 = wp[0], w1 = wp[1];
            const float wf[8] = {w0.x, w0.y, w0.z, w0.w, w1.x, w1.y, w1.z, w1.w};
            #pragma unroll
            for (int jj = 0; jj < 8; ++jj) {
                h[0][jj] += as0[dk] * wf[jj];
                h[1][jj] += as1[dk] * wf[jj];
            }
        }
    }

    // exact gelu
    #pragma unroll
    for (int r = 0; r < 2; ++r)
        #pragma unroll
        for (int jj = 0; jj < 8; ++jj) {
            float x = h[r][jj];
            h[r][jj] = 0.5f * x * (1.0f + erff(x * 0.70710678118654752f));
        }

    // sparse gather: W[n, (n+off)&1023] = h[n] . W2T[(n+off)&1023]
    const int rbase = nl * 2;
    #pragma unroll
    for (int r = 0; r < 2; ++r) {
        #pragma unroll
        for (int o = 0; o < NOFF; ++o) {
            int slot;
            if (o == 0) slot = rbase + r;
            else {
                int off = 1 << (o - 1);
                slot = (off <= 16) ? (rbase + r + off)
                                   : (24 + 8 * (o - 6) + rbase + r);
            }
            const float4* gp = (const float4*)(sW2r + slot * W2PAD + j0);
            float4 g0 = gp[0], g1 = gp[1];
            float w = h[r][0] * g0.x + h[r][1] * g0.y + h[r][2] * g0.z + h[r][3] * g0.w
                    + h[r][4] * g1.x + h[r][5] * g1.y + h[r][6] * g1.z + h[r][7] * g1.w;
            w += __shfl_xor(w, 16, 64);   // combine jq bit 0
            w += __shfl_xor(w, 32, 64);   // combine jq bit 1
            if (jq == (o & 3))
                rws[(b * 8 + rbase + r) * WPAD + o] = w + sb2[slot];
        }
    }
    __syncthreads();

    // coalesced write-out: 128 rows x 12 floats = 384 float4
    {
        const float4* rv = (const float4*)rws;
        #pragma unroll
        for (int k = t; k < 128 * 3; k += 256) {
            int row = k / 3, comp = k - row * 3;
            int bb = row >> 3, nloc = row & 7;
            float4* dst = (float4*)(Wsp +
                ((size_t)(i * BATCH + bb) * NVEC + nbase + nloc) * WPAD + comp * 4);
            *dst = rv[k];
        }
    }
}

// ---------------------------------------------------------------------------
// Kernel 2: FUSED 10-layer chain + final-projection partials + final
// reduction by the last-arriving block per batch (threadfence + atomic
// counter; summation order identical to the old k_finish: bias first, then
// chunks 0..15 ascending -> bitwise-identical output). Own V element kept
// in a register (vown): 10 LDS reads + 1 write per layer instead of 11+1.
// grid (16 chunks, BATCH), block 1024.
// ---------------------------------------------------------------------------
__global__ __launch_bounds__(1024) void k_chain(
    const float* __restrict__ data,   // [B][NVEC][NDIM]
    const float* __restrict__ Wsp,    // [NW][B][NVEC][WPAD]
    const float* __restrict__ Wf,     // [NVEC*NDIM][NCLS]
    const float* __restrict__ bias,   // [NCLS]
    float* __restrict__ part,         // [B][NCHUNK][NCLS]
    int* __restrict__ cnt,            // [BATCH]
    float* __restrict__ out)          // [B][NCLS]
{
    const int chunk = blockIdx.x;
    const int b     = blockIdx.y;
    const int d0    = chunk * 4;
    const int n     = threadIdx.x;

    __shared__ float4 bufA[NVEC];
    __shared__ float4 bufB[NVEC];
    __shared__ int sdone;

    float4 vown = *(const float4*)(data + ((size_t)(b * NVEC) + n) * NDIM + d0);
    bufA[n] = vown;

    // prefetch layer NW-1 weights
    const float4* wp = (const float4*)(Wsp + ((size_t)((NW - 1) * BATCH + b) * NVEC + n) * WPAD);
    float4 wa = wp[0], wb4 = wp[1], wc = wp[2];
    __syncthreads();

    float4* cur = bufA;
    float4* nxt = bufB;

    for (int l = 0; l < NW; ++l) {
        float4 na, nb, nc;
        if (l < NW - 1) {   // prefetch next layer (in flight across barrier)
            const float4* wpn = (const float4*)(
                Wsp + ((size_t)((NW - 2 - l) * BATCH + b) * NVEC + n) * WPAD);
            na = wpn[0]; nb = wpn[1]; nc = wpn[2];
        }
        const float wgt[12] = {wa.x, wa.y, wa.z, wa.w,
                               wb4.x, wb4.y, wb4.z, wb4.w,
                               wc.x, wc.y, wc.z, wc.w};
        float4 v0 = vown;                 // == cur[n], kept in register
        float4 acc;
        acc.x = v0.x + wgt[0] * v0.x;
        acc.y = v0.y + wgt[0] * v0.y;
        acc.z = v0.z + wgt[0] * v0.z;
        acc.w = v0.w + wgt[0] * v0.w;
        #pragma unroll
        for (int o = 1; o < NOFF; ++o) {
            int off = 1 << (o - 1);
            float4 vv = cur[(n + off) & (NVEC - 1)];
            acc.x += wgt[o] * vv.x; acc.y += wgt[o] * vv.y;
            acc.z += wgt[o] * vv.z; acc.w += wgt[o] * vv.w;
        }
        nxt[n] = acc;
        vown = acc;
        __syncthreads();
        float4* tmp = cur; cur = nxt; nxt = tmp;
        if (l < NW - 1) { wa = na; wb4 = nb; wc = nc; }
    }

    // fused final projection partial over this (b, d-chunk) — from register
    float p[NCLS];
    #pragma unroll
    for (int c = 0; c < NCLS; ++c) p[c] = 0.0f;
    {
        float vs[4] = {vown.x, vown.y, vown.z, vown.w};
        const float4* wfv = (const float4*)(Wf + ((size_t)(n * NDIM + d0)) * NCLS);
        float wf[40];
        #pragma unroll
        for (int k = 0; k < 10; ++k) {
            float4 u = wfv[k];
            wf[k * 4 + 0] = u.x; wf[k * 4 + 1] = u.y;
            wf[k * 4 + 2] = u.z; wf[k * 4 + 3] = u.w;
        }
        #pragma unroll
        for (int d = 0; d < 4; ++d)
            #pragma unroll
            for (int cls = 0; cls < NCLS; ++cls)
                p[cls] += vs[d] * wf[d * NCLS + cls];
    }

    // reduce 1024 threads -> 10 values: wave shfl then cross-wave via LDS
    const int lane = n & 63, wv = n >> 6;   // 16 waves
    float* sred = (float*)nxt;              // dead buffer (post-final-barrier)
    #pragma unroll
    for (int cls = 0; cls < NCLS; ++cls) {
        float v = p[cls];
        #pragma unroll
        for (int s = 32; s > 0; s >>= 1) v += __shfl_down(v, s, 64);
        if (lane == 0) sred[wv * NCLS + cls] = v;
    }
    __syncthreads();
    if (n < NCLS) {
        float s = 0.0f;
        #pragma unroll
        for (int w = 0; w < 16; ++w) s += sred[w * NCLS + n];
        part[(size_t)(b * NCHUNK + chunk) * NCLS + n] = s;
    }

    // last-arriving block per b performs the old k_finish
    __threadfence();            // make this block's part[] visible (device scope)
    __syncthreads();            // fences of storing threads complete first
    if (n == 0) {
        int old = atomicAdd(cnt + b, 1);   // device-scope by default on CDNA
        sdone = (old == NCHUNK - 1);
    }
    __syncthreads();
    if (sdone && n < NCLS) {
        float s = bias[n];
        #pragma unroll
        for (int ch = 0; ch < NCHUNK; ++ch)
            s += part[(size_t)(b * NCHUNK + ch) * NCLS + n];
        out[b * NCLS + n] = s;
    }
}

// ---------------------------------------------------------------------------
extern "C" void kernel_launch(void* const* d_in, const int* in_sizes, int n_in,
                              void* d_out, int out_size, void* d_ws, size_t ws_size,
                              hipStream_t stream) {
    const float* data = (const float*)d_in[0];
    const float* fW1  = (const float*)d_in[1];
    const float* fb1  = (const float*)d_in[2];
    const float* fW2  = (const float*)d_in[3];
    const float* fb2  = (const float*)d_in[4];
    const float* fWf  = (const float*)d_in[5];
    const float* fbf  = (const float*)d_in[6];
    float* out = (float*)d_out;

    float* ws   = (float*)d_ws;
    float* Wsp  = ws;                                         // NW*B*NVEC*WPAD = 1,966,080 f
    float* part = Wsp + (size_t)NW * BATCH * NVEC * WPAD;     // B*NCHUNK*NCLS = 2,560 f
    int*   cnt  = (int*)(part + (size_t)BATCH * NCHUNK * NCLS);

    k_weights<<<dim3(NVEC / 8, NW), 256, 0, stream>>>(
        data, fW1, fb1, fW2, fb2, Wsp, cnt);
    k_chain<<<dim3(NCHUNK, BATCH), 1024, 0, stream>>>(
        data, Wsp, fWf, fbf, part, cnt, out);
}

// Round 3
// 120.738 us; speedup vs baseline: 1.4596x; 1.4596x over previous
//
#include <hip/hip_runtime.h>

// Problem constants (from reference setup_inputs) — all tensors are fp32.
#define BATCH 16
#define NVEC 1024
#define NDIM 64
#define NHID 32
#define NW   10
#define NCLS 10
#define NOFF 11      // diag + 10 power-of-2 offsets (chord mask: 11 nnz/row)
#define WPAD 12      // padded weights-per-row so k_chain reads 3x float4
#define NCHUNK (NDIM / 4)   // 16 d-chunks in k_chain
#define W2PAD 36     // padded row length for the 64-row LDS W2 cache

// ---------------------------------------------------------------------------
// Kernel 1 (fused transpose + weights): all sparse chord weights, all 10
// layers. Block = (layer i, 8 rows, ALL 16 b). Thread = (b = t&15,
// jq = (t>>4)&3, nl = t>>6) computing 2 rows x 8 hidden -> h[2][8].
//
//  * Each block needs exactly 64 W2T rows
//    (k in [0,24) u ({32,64,128,256,512}+[0,8)) relative to nbase), staged
//    into LDS directly from fW2 (8 scalar loads/thread, 32B-coalesced) —
//    no separate transpose kernel.
//  * Row weights accumulate in a 6 KB LDS buffer, written out as 384
//    coalesced float4 per block.
//  * NOTE (round-2 post-mortem): do NOT fuse the final reduction into
//    k_chain — the required __threadfence() is a whole-L2 writeback/inv on
//    gfx950; 256 blocks executing it while others run cost +50 µs
//    (k_chain FETCH_SIZE 49 MB, pure cache-thrash).
// grid (NVEC/8, NW), block 256.
// ---------------------------------------------------------------------------
__global__ __launch_bounds__(256) void k_weights(
    const float* __restrict__ data,   // [B][NVEC][NDIM]
    const float* __restrict__ fW1,    // [NW][NDIM][NHID]
    const float* __restrict__ fb1,    // [NW][NHID]
    const float* __restrict__ fW2,    // [NW][NHID][NVEC]
    const float* __restrict__ fb2,    // [NW][NVEC]
    float* __restrict__ Wsp)          // [NW][B][NVEC][WPAD]
{
    const int i = blockIdx.y;
    const int nbase = blockIdx.x * 8;
    const int t = threadIdx.x;
    const int b  = t & 15;
    const int jq = (t >> 4) & 3;
    const int nl = t >> 6;            // wave index; lane = b + 16*jq
    const int j0 = jq * 8;

    __shared__ __align__(16) float sW1[NDIM * NHID];   // [d][j], 8 KB
    __shared__ float sb1[NHID];
    __shared__ __align__(16) float sW2r[64 * W2PAD];   // 64 gather rows, 9 KB
    __shared__ float sb2[64];                          // fb2 at those rows
    __shared__ __align__(16) float rws[128 * WPAD];    // row weights, 6 KB

    {
        const float4* w1v = (const float4*)(fW1 + (size_t)i * NDIM * NHID);
        float4* s4 = (float4*)sW1;
        #pragma unroll
        for (int k = t; k < NDIM * NHID / 4; k += 256) s4[k] = w1v[k];
        if (t < NHID) sb1[t] = fb1[i * NHID + t];

        // stage the 64 needed fW2 columns (rows of W2^T) into LDS
        const int j  = t >> 3;
        const int s0 = t & 7;
        const float* w2 = fW2 + ((size_t)i * NHID + j) * NVEC;
        #pragma unroll
        for (int c = 0; c < 8; ++c) {
            int s = s0 + c * 8;
            int k = (s < 24) ? s : ((32 << ((s - 24) >> 3)) + ((s - 24) & 7));
            int m = (nbase + k) & (NVEC - 1);
            sW2r[s * W2PAD + j] = w2[m];               // 8-lane 32B segments
        }
        if (t < 64) {
            int s = t;
            int k = (s < 24) ? s : ((32 << ((s - 24) >> 3)) + ((s - 24) & 7));
            int m = (nbase + k) & (NVEC - 1);
            sb2[s] = fb2[(size_t)i * NVEC + m];
        }
        // zero the WPAD pad slot so Wsp never carries stale-LDS bits
        for (int k = t; k < 128; k += 256) rws[k * WPAD + (WPAD - 1)] = 0.0f;
    }
    __syncthreads();

    float h[2][8];
    #pragma unroll
    for (int r = 0; r < 2; ++r)
        #pragma unroll
        for (int jj = 0; jj < 8; ++jj) h[r][jj] = sb1[j0 + jj];

    const int n0 = nbase + nl * 2;
    const float4* arow0 = (const float4*)(data + ((size_t)(b * NVEC) + n0) * NDIM);
    const float4* arow1 = (const float4*)(data + ((size_t)(b * NVEC) + n0 + 1) * NDIM);

    #pragma unroll 4
    for (int g = 0; g < 16; ++g) {       // 4 d-dims per iteration
        float4 a0 = arow0[g];
        float4 a1 = arow1[g];
        float as0[4] = {a0.x, a0.y, a0.z, a0.w};
        float as1[4] = {a1.x, a1.y, a1.z, a1.w};
        #pragma unroll
        for (int dk = 0; dk < 4; ++dk) {
            const float4* wp = (const float4*)(&sW1[(g * 4 + dk) * NHID + j0]);
            float4 w0 = wp[0], w1 = wp[1];
            const float wf[8] = {w0.x, w0.y, w0.z, w0.w, w1.x, w1.y, w1.z, w1.w};
            #pragma unroll
            for (int jj = 0; jj < 8; ++jj) {
                h[0][jj] += as0[dk] * wf[jj];
                h[1][jj] += as1[dk] * wf[jj];
            }
        }
    }

    // exact gelu
    #pragma unroll
    for (int r = 0; r < 2; ++r)
        #pragma unroll
        for (int jj = 0; jj < 8; ++jj) {
            float x = h[r][jj];
            h[r][jj] = 0.5f * x * (1.0f + erff(x * 0.70710678118654752f));
        }

    // sparse gather: W[n, (n+off)&1023] = h[n] . W2T[(n+off)&1023]
    const int rbase = nl * 2;
    #pragma unroll
    for (int r = 0; r < 2; ++r) {
        #pragma unroll
        for (int o = 0; o < NOFF; ++o) {
            int slot;
            if (o == 0) slot = rbase + r;
            else {
                int off = 1 << (o - 1);
                slot = (off <= 16) ? (rbase + r + off)
                                   : (24 + 8 * (o - 6) + rbase + r);
            }
            const float4* gp = (const float4*)(sW2r + slot * W2PAD + j0);
            float4 g0 = gp[0], g1 = gp[1];
            float w = h[r][0] * g0.x + h[r][1] * g0.y + h[r][2] * g0.z + h[r][3] * g0.w
                    + h[r][4] * g1.x + h[r][5] * g1.y + h[r][6] * g1.z + h[r][7] * g1.w;
            w += __shfl_xor(w, 16, 64);   // combine jq bit 0
            w += __shfl_xor(w, 32, 64);   // combine jq bit 1
            if (jq == (o & 3))
                rws[(b * 8 + rbase + r) * WPAD + o] = w + sb2[slot];
        }
    }
    __syncthreads();

    // coalesced write-out: 128 rows x 12 floats = 384 float4
    {
        const float4* rv = (const float4*)rws;
        #pragma unroll
        for (int k = t; k < 128 * 3; k += 256) {
            int row = k / 3, comp = k - row * 3;
            int bb = row >> 3, nloc = row & 7;
            float4* dst = (float4*)(Wsp +
                ((size_t)(i * BATCH + bb) * NVEC + nbase + nloc) * WPAD + comp * 4);
            *dst = rv[k];
        }
    }
}

// ---------------------------------------------------------------------------
// Kernel 2: FUSED 10-layer chain + final-projection partials.
// Block = (b, 4-dim chunk): V[1024][4] slice closed under the chord gather,
// kept in LDS float4. Own V element in a register (vown): 10 LDS reads + 1
// write per layer. Next layer's weights prefetched across the barrier.
// XCD-aware mapping: 1-D grid, xcd = lin&7 — all 16 chunk-blocks of a b
// land on one XCD, so each layer's 48 KB Wsp slab is fetched once per XCD
// and reused 16x from L2 (grid(16,16) spread them over all 8 XCDs).
// grid (256), block 1024.
// ---------------------------------------------------------------------------
__global__ __launch_bounds__(1024) void k_chain(
    const float* __restrict__ data,   // [B][NVEC][NDIM]
    const float* __restrict__ Wsp,    // [NW][B][NVEC][WPAD]
    const float* __restrict__ Wf,     // [NVEC*NDIM][NCLS]
    float* __restrict__ part)         // [B][NCHUNK][NCLS]
{
    const int lin   = blockIdx.x;
    const int xcd   = lin & 7;
    const int slot  = lin >> 3;             // 0..31
    const int b     = (xcd << 1) | (slot >> 4);
    const int chunk = slot & 15;
    const int d0    = chunk * 4;
    const int n     = threadIdx.x;

    __shared__ float4 bufA[NVEC];
    __shared__ float4 bufB[NVEC];

    float4 vown = *(const float4*)(data + ((size_t)(b * NVEC) + n) * NDIM + d0);
    bufA[n] = vown;

    // prefetch layer NW-1 weights
    const float4* wp = (const float4*)(Wsp + ((size_t)((NW - 1) * BATCH + b) * NVEC + n) * WPAD);
    float4 wa = wp[0], wb4 = wp[1], wc = wp[2];
    __syncthreads();

    float4* cur = bufA;
    float4* nxt = bufB;

    for (int l = 0; l < NW; ++l) {
        float4 na, nb, nc;
        if (l < NW - 1) {   // prefetch next layer (in flight across barrier)
            const float4* wpn = (const float4*)(
                Wsp + ((size_t)((NW - 2 - l) * BATCH + b) * NVEC + n) * WPAD);
            na = wpn[0]; nb = wpn[1]; nc = wpn[2];
        }
        const float wgt[12] = {wa.x, wa.y, wa.z, wa.w,
                               wb4.x, wb4.y, wb4.z, wb4.w,
                               wc.x, wc.y, wc.z, wc.w};
        float4 v0 = vown;                 // == cur[n], kept in register
        float4 acc;
        acc.x = v0.x + wgt[0] * v0.x;
        acc.y = v0.y + wgt[0] * v0.y;
        acc.z = v0.z + wgt[0] * v0.z;
        acc.w = v0.w + wgt[0] * v0.w;
        #pragma unroll
        for (int o = 1; o < NOFF; ++o) {
            int off = 1 << (o - 1);
            float4 vv = cur[(n + off) & (NVEC - 1)];
            acc.x += wgt[o] * vv.x; acc.y += wgt[o] * vv.y;
            acc.z += wgt[o] * vv.z; acc.w += wgt[o] * vv.w;
        }
        nxt[n] = acc;
        vown = acc;
        __syncthreads();
        float4* tmp = cur; cur = nxt; nxt = tmp;
        if (l < NW - 1) { wa = na; wb4 = nb; wc = nc; }
    }

    // fused final projection partial over this (b, d-chunk) — from register
    float p[NCLS];
    #pragma unroll
    for (int c = 0; c < NCLS; ++c) p[c] = 0.0f;
    {
        float vs[4] = {vown.x, vown.y, vown.z, vown.w};
        const float4* wfv = (const float4*)(Wf + ((size_t)(n * NDIM + d0)) * NCLS);
        float wf[40];
        #pragma unroll
        for (int k = 0; k < 10; ++k) {
            float4 u = wfv[k];
            wf[k * 4 + 0] = u.x; wf[k * 4 + 1] = u.y;
            wf[k * 4 + 2] = u.z; wf[k * 4 + 3] = u.w;
        }
        #pragma unroll
        for (int d = 0; d < 4; ++d)
            #pragma unroll
            for (int cls = 0; cls < NCLS; ++cls)
                p[cls] += vs[d] * wf[d * NCLS + cls];
    }

    // reduce 1024 threads -> 10 values: wave shfl then cross-wave via LDS
    const int lane = n & 63, wv = n >> 6;   // 16 waves
    float* sred = (float*)nxt;              // dead buffer
    #pragma unroll
    for (int cls = 0; cls < NCLS; ++cls) {
        float v = p[cls];
        #pragma unroll
        for (int s = 32; s > 0; s >>= 1) v += __shfl_down(v, s, 64);
        if (lane == 0) sred[wv * NCLS + cls] = v;
    }
    __syncthreads();
    if (n < NCLS) {
        float s = 0.0f;
        #pragma unroll
        for (int w = 0; w < 16; ++w) s += sred[w * NCLS + n];
        part[(size_t)(b * NCHUNK + chunk) * NCLS + n] = s;
    }
}

// ---------------------------------------------------------------------------
__global__ __launch_bounds__(256) void k_finish(
    const float* __restrict__ part, const float* __restrict__ bias,
    float* __restrict__ out)
{
    int t = threadIdx.x;
    if (t < BATCH * NCLS) {
        int b = t / NCLS, cls = t % NCLS;
        float s = bias[cls];
        #pragma unroll
        for (int ch = 0; ch < NCHUNK; ++ch)
            s += part[(size_t)(b * NCHUNK + ch) * NCLS + cls];
        out[t] = s;
    }
}

// ---------------------------------------------------------------------------
extern "C" void kernel_launch(void* const* d_in, const int* in_sizes, int n_in,
                              void* d_out, int out_size, void* d_ws, size_t ws_size,
                              hipStream_t stream) {
    const float* data = (const float*)d_in[0];
    const float* fW1  = (const float*)d_in[1];
    const float* fb1  = (const float*)d_in[2];
    const float* fW2  = (const float*)d_in[3];
    const float* fb2  = (const float*)d_in[4];
    const float* fWf  = (const float*)d_in[5];
    const float* fbf  = (const float*)d_in[6];
    float* out = (float*)d_out;

    float* ws   = (float*)d_ws;
    float* Wsp  = ws;                                         // NW*B*NVEC*WPAD = 1,966,080 f
    float* part = Wsp + (size_t)NW * BATCH * NVEC * WPAD;     // B*NCHUNK*NCLS = 2,560 f

    k_weights<<<dim3(NVEC / 8, NW), 256, 0, stream>>>(
        data, fW1, fb1, fW2, fb2, Wsp);
    k_chain<<<dim3(NCHUNK * BATCH), 1024, 0, stream>>>(data, Wsp, fWf, part);
    k_finish<<<dim3(1), 256, 0, stream>>>(part, fbf, out);
}

// Round 4
// 115.805 us; speedup vs baseline: 1.5217x; 1.0426x over previous
//
#include <hip/hip_runtime.h>

// Problem constants (from reference setup_inputs) — all tensors are fp32.
#define BATCH 16
#define NVEC 1024
#define NDIM 64
#define NHID 32
#define NW   10
#define NCLS 10
#define NOFF 11      // diag + 10 power-of-2 offsets (chord mask: 11 nnz/row)
#define WPAD 12      // padded weights-per-row so k_chain reads 3x float4
#define NCHUNK (NDIM / 4)   // 16 d-chunks in k_chain
#define W2PAD 36     // padded row length for the staged-W2 LDS cache
#define NROW 16      // n-rows per k_weights block (4 per thread)
#define NSLOT 112    // staged W2T rows: [0,32) u ({32,64,128,256,512}+[0,16))

// ---------------------------------------------------------------------------
// Kernel 1: all sparse chord weights, all 10 layers.
// Block = (layer i, 16 rows, ALL 16 b); grid (64, 10), 256 threads.
// Thread = (jq = t&3, b = (t>>2)&15, nl = t>>6) computing 4 consecutive
// rows x 8 hidden units -> h[4][8].
//
// Session journal:
//  * jq in lane bits 0-1 so the quarter-dot reduction is shfl_xor(1)/(2)
//    = DPP quad_perm (pure VALU) instead of ds_swizzle via the LDS pipe.
//    Reduction order (q0+q1)+(q2+q3) per jq preserved -> bitwise identical.
//  * 4 rows/thread halves total W1 ds_read_b128 traffic (per-thread W1
//    bytes are constant; rows/thread is the only amortization lever).
//  * nl is the wave index -> gather slot is wave-uniform (broadcast reads).
//  * round-2 post-mortem: NEVER fuse the final reduction via __threadfence
//    — it is a whole-L2 writeback/inv on gfx950 (cost +50 µs).
// ---------------------------------------------------------------------------
__global__ __launch_bounds__(256, 4) void k_weights(
    const float* __restrict__ data,   // [B][NVEC][NDIM]
    const float* __restrict__ fW1,    // [NW][NDIM][NHID]
    const float* __restrict__ fb1,    // [NW][NHID]
    const float* __restrict__ fW2,    // [NW][NHID][NVEC]
    const float* __restrict__ fb2,    // [NW][NVEC]
    float* __restrict__ Wsp)          // [NW][B][NVEC][WPAD]
{
    const int i = blockIdx.y;
    const int nbase = blockIdx.x * NROW;
    const int t = threadIdx.x;
    const int jq = t & 3;
    const int b  = (t >> 2) & 15;
    const int nl = t >> 6;            // wave index 0..3 (4 rows each)
    const int j0 = jq * 8;

    __shared__ __align__(16) float sW1[NDIM * NHID];        // [d][j], 8 KB
    __shared__ float sb1[NHID];
    __shared__ __align__(16) float sW2r[NSLOT * W2PAD];     // 16.1 KB
    __shared__ float sb2[NSLOT];                            // fb2 at slots
    __shared__ __align__(16) float rws[NROW * BATCH * WPAD];// 12 KB

    {
        const float4* w1v = (const float4*)(fW1 + (size_t)i * NDIM * NHID);
        float4* s4 = (float4*)sW1;
        #pragma unroll
        for (int k = t; k < NDIM * NHID / 4; k += 256) s4[k] = w1v[k];
        if (t < NHID) sb1[t] = fb1[i * NHID + t];

        // stage the 112 needed fW2 columns (rows of W2^T) into LDS
        const int j  = t >> 3;        // 0..31
        const int s0 = t & 7;
        const float* w2 = fW2 + ((size_t)i * NHID + j) * NVEC;
        #pragma unroll
        for (int c = 0; c < NSLOT / 8; ++c) {
            int s = s0 + c * 8;
            int k = (s < 32) ? s : ((32 << ((s - 32) >> 4)) + ((s - 32) & 15));
            int m = (nbase + k) & (NVEC - 1);
            sW2r[s * W2PAD + j] = w2[m];           // 8-lane 32B segments
        }
        if (t < NSLOT) {
            int s = t;
            int k = (s < 32) ? s : ((32 << ((s - 32) >> 4)) + ((s - 32) & 15));
            int m = (nbase + k) & (NVEC - 1);
            sb2[s] = fb2[(size_t)i * NVEC + m];
        }
        // zero the WPAD pad slot so Wsp never carries stale-LDS bits
        for (int k = t; k < NROW * BATCH; k += 256) rws[k * WPAD + (WPAD - 1)] = 0.0f;
    }
    __syncthreads();

    float h[4][8];
    #pragma unroll
    for (int r = 0; r < 4; ++r)
        #pragma unroll
        for (int jj = 0; jj < 8; ++jj) h[r][jj] = sb1[j0 + jj];

    const int n0 = nbase + nl * 4;    // 4 consecutive rows -> one base ptr
    const float4* rowp = (const float4*)(data + ((size_t)(b * NVEC) + n0) * NDIM);

    #pragma unroll 2
    for (int g = 0; g < 16; ++g) {    // 4 d-dims per iteration
        float4 a0 = rowp[g];
        float4 a1 = rowp[16 + g];
        float4 a2 = rowp[32 + g];
        float4 a3 = rowp[48 + g];
        const float as[4][4] = {{a0.x, a0.y, a0.z, a0.w},
                                {a1.x, a1.y, a1.z, a1.w},
                                {a2.x, a2.y, a2.z, a2.w},
                                {a3.x, a3.y, a3.z, a3.w}};
        #pragma unroll
        for (int dk = 0; dk < 4; ++dk) {
            const float4* wp = (const float4*)(&sW1[(g * 4 + dk) * NHID + j0]);
            float4 w0 = wp[0], w1 = wp[1];
            const float wf[8] = {w0.x, w0.y, w0.z, w0.w, w1.x, w1.y, w1.z, w1.w};
            #pragma unroll
            for (int jj = 0; jj < 8; ++jj) {
                h[0][jj] += as[0][dk] * wf[jj];
                h[1][jj] += as[1][dk] * wf[jj];
                h[2][jj] += as[2][dk] * wf[jj];
                h[3][jj] += as[3][dk] * wf[jj];
            }
        }
    }

    // exact gelu (bit-match with reference)
    #pragma unroll
    for (int r = 0; r < 4; ++r)
        #pragma unroll
        for (int jj = 0; jj < 8; ++jj) {
            float x = h[r][jj];
            h[r][jj] = 0.5f * x * (1.0f + erff(x * 0.70710678118654752f));
        }

    // sparse gather: W[n, (n+off)&1023] = h[n] . W2T[(n+off)&1023] + b2
    const int rbase = nl * 4;
    #pragma unroll
    for (int r = 0; r < 4; ++r) {
        #pragma unroll
        for (int o = 0; o < NOFF; ++o) {
            int slot;
            if (o == 0) slot = rbase + r;
            else {
                int off = 1 << (o - 1);
                slot = (off <= 16) ? (rbase + r + off)
                                   : (32 + 16 * (o - 6) + rbase + r);
            }
            const float4* gp = (const float4*)(sW2r + slot * W2PAD + j0);
            float4 g0 = gp[0], g1 = gp[1];
            float w = h[r][0] * g0.x + h[r][1] * g0.y + h[r][2] * g0.z + h[r][3] * g0.w
                    + h[r][4] * g1.x + h[r][5] * g1.y + h[r][6] * g1.z + h[r][7] * g1.w;
            w += __shfl_xor(w, 1, 64);    // combine jq bit 0 (DPP quad_perm)
            w += __shfl_xor(w, 2, 64);    // combine jq bit 1 (DPP quad_perm)
            if (jq == (o & 3))
                rws[(b * NROW + rbase + r) * WPAD + o] = w + sb2[slot];
        }
    }
    __syncthreads();

    // coalesced write-out: 256 rows x 12 floats = 768 float4
    {
        const float4* rv = (const float4*)rws;
        #pragma unroll
        for (int k = t; k < NROW * BATCH * 3; k += 256) {
            int row = k / 3, comp = k - row * 3;
            int bb = row >> 4, rr = row & 15;
            float4* dst = (float4*)(Wsp +
                ((size_t)(i * BATCH + bb) * NVEC + nbase + rr) * WPAD + comp * 4);
            *dst = rv[k];
        }
    }
}

// ---------------------------------------------------------------------------
// Kernel 2: FUSED 10-layer chain + final-projection partials.
// Block = (b, 4-dim chunk): V[1024][4] slice closed under the chord gather,
// kept in LDS float4. Own V element in a register (vown): 10 LDS reads + 1
// write per layer. Next layer's weights prefetched across the barrier.
// XCD-aware mapping: 1-D grid, xcd = lin&7 — all 16 chunk-blocks of a b
// land on one XCD, so each layer's 48 KB Wsp slab is fetched once per XCD
// and reused 16x from L2.
// grid (256), block 1024.
// ---------------------------------------------------------------------------
__global__ __launch_bounds__(1024) void k_chain(
    const float* __restrict__ data,   // [B][NVEC][NDIM]
    const float* __restrict__ Wsp,    // [NW][B][NVEC][WPAD]
    const float* __restrict__ Wf,     // [NVEC*NDIM][NCLS]
    float* __restrict__ part)         // [B][NCHUNK][NCLS]
{
    const int lin   = blockIdx.x;
    const int xcd   = lin & 7;
    const int slot  = lin >> 3;             // 0..31
    const int b     = (xcd << 1) | (slot >> 4);
    const int chunk = slot & 15;
    const int d0    = chunk * 4;
    const int n     = threadIdx.x;

    __shared__ float4 bufA[NVEC];
    __shared__ float4 bufB[NVEC];

    float4 vown = *(const float4*)(data + ((size_t)(b * NVEC) + n) * NDIM + d0);
    bufA[n] = vown;

    // prefetch layer NW-1 weights
    const float4* wp = (const float4*)(Wsp + ((size_t)((NW - 1) * BATCH + b) * NVEC + n) * WPAD);
    float4 wa = wp[0], wb4 = wp[1], wc = wp[2];
    __syncthreads();

    float4* cur = bufA;
    float4* nxt = bufB;

    for (int l = 0; l < NW; ++l) {
        float4 na, nb, nc;
        if (l < NW - 1) {   // prefetch next layer (in flight across barrier)
            const float4* wpn = (const float4*)(
                Wsp + ((size_t)((NW - 2 - l) * BATCH + b) * NVEC + n) * WPAD);
            na = wpn[0]; nb = wpn[1]; nc = wpn[2];
        }
        const float wgt[12] = {wa.x, wa.y, wa.z, wa.w,
                               wb4.x, wb4.y, wb4.z, wb4.w,
                               wc.x, wc.y, wc.z, wc.w};
        float4 v0 = vown;                 // == cur[n], kept in register
        float4 acc;
        acc.x = v0.x + wgt[0] * v0.x;
        acc.y = v0.y + wgt[0] * v0.y;
        acc.z = v0.z + wgt[0] * v0.z;
        acc.w = v0.w + wgt[0] * v0.w;
        #pragma unroll
        for (int o = 1; o < NOFF; ++o) {
            int off = 1 << (o - 1);
            float4 vv = cur[(n + off) & (NVEC - 1)];
            acc.x += wgt[o] * vv.x; acc.y += wgt[o] * vv.y;
            acc.z += wgt[o] * vv.z; acc.w += wgt[o] * vv.w;
        }
        nxt[n] = acc;
        vown = acc;
        __syncthreads();
        float4* tmp = cur; cur = nxt; nxt = tmp;
        if (l < NW - 1) { wa = na; wb4 = nb; wc = nc; }
    }

    // fused final projection partial over this (b, d-chunk) — from register
    float p[NCLS];
    #pragma unroll
    for (int c = 0; c < NCLS; ++c) p[c] = 0.0f;
    {
        float vs[4] = {vown.x, vown.y, vown.z, vown.w};
        const float4* wfv = (const float4*)(Wf + ((size_t)(n * NDIM + d0)) * NCLS);
        float wf[40];
        #pragma unroll
        for (int k = 0; k < 10; ++k) {
            float4 u = wfv[k];
            wf[k * 4 + 0] = u.x; wf[k * 4 + 1] = u.y;
            wf[k * 4 + 2] = u.z; wf[k * 4 + 3] = u.w;
        }
        #pragma unroll
        for (int d = 0; d < 4; ++d)
            #pragma unroll
            for (int cls = 0; cls < NCLS; ++cls)
                p[cls] += vs[d] * wf[d * NCLS + cls];
    }

    // reduce 1024 threads -> 10 values: wave shfl then cross-wave via LDS
    const int lane = n & 63, wv = n >> 6;   // 16 waves
    float* sred = (float*)nxt;              // dead buffer
    #pragma unroll
    for (int cls = 0; cls < NCLS; ++cls) {
        float v = p[cls];
        #pragma unroll
        for (int s = 32; s > 0; s >>= 1) v += __shfl_down(v, s, 64);
        if (lane == 0) sred[wv * NCLS + cls] = v;
    }
    __syncthreads();
    if (n < NCLS) {
        float s = 0.0f;
        #pragma unroll
        for (int w = 0; w < 16; ++w) s += sred[w * NCLS + n];
        part[(size_t)(b * NCHUNK + chunk) * NCLS + n] = s;
    }
}

// ---------------------------------------------------------------------------
__global__ __launch_bounds__(256) void k_finish(
    const float* __restrict__ part, const float* __restrict__ bias,
    float* __restrict__ out)
{
    int t = threadIdx.x;
    if (t < BATCH * NCLS) {
        int b = t / NCLS, cls = t % NCLS;
        float s = bias[cls];
        #pragma unroll
        for (int ch = 0; ch < NCHUNK; ++ch)
            s += part[(size_t)(b * NCHUNK + ch) * NCLS + cls];
        out[t] = s;
    }
}

// ---------------------------------------------------------------------------
extern "C" void kernel_launch(void* const* d_in, const int* in_sizes, int n_in,
                              void* d_out, int out_size, void* d_ws, size_t ws_size,
                              hipStream_t stream) {
    const float* data = (const float*)d_in[0];
    const float* fW1  = (const float*)d_in[1];
    const float* fb1  = (const float*)d_in[2];
    const float* fW2  = (const float*)d_in[3];
    const float* fb2  = (const float*)d_in[4];
    const float* fWf  = (const float*)d_in[5];
    const float* fbf  = (const float*)d_in[6];
    float* out = (float*)d_out;

    float* ws   = (float*)d_ws;
    float* Wsp  = ws;                                         // NW*B*NVEC*WPAD = 1,966,080 f
    float* part = Wsp + (size_t)NW * BATCH * NVEC * WPAD;     // B*NCHUNK*NCLS = 2,560 f

    k_weights<<<dim3(NVEC / NROW, NW), 256, 0, stream>>>(
        data, fW1, fb1, fW2, fb2, Wsp);
    k_chain<<<dim3(NCHUNK * BATCH), 1024, 0, stream>>>(data, Wsp, fWf, part);
    k_finish<<<dim3(1), 256, 0, stream>>>(part, fbf, out);
}

// Round 5
// 115.001 us; speedup vs baseline: 1.5324x; 1.0070x over previous
//
#include <hip/hip_runtime.h>

// Problem constants (from reference setup_inputs) — all tensors are fp32.
#define BATCH 16
#define NVEC 1024
#define NDIM 64
#define NHID 32
#define NW   10
#define NCLS 10
#define NOFF 11      // diag + 10 power-of-2 offsets (chord mask: 11 nnz/row)
#define WPAD 12      // padded weights-per-row so k_chain reads 3x float4
#define NCHUNK (NDIM / 4)   // 16 d-chunks in k_chain
#define W2PAD 36     // padded row length for the staged-W2 LDS cache
#define NROW 8       // n-rows per k_weights block (4 per thread, 2 waves)
#define NSLOT 64     // staged W2T rows: [0,24) u ({32,64,128,256,512}+[0,8))

// ---------------------------------------------------------------------------
// Kernel 1: all sparse chord weights, all 10 layers.
// Block = (layer i, 8 rows, ALL 16 b); grid (128, 10) = 1280 blocks of 128
// threads = EXACTLY 5 blocks/CU (round-4 640-block grid was 2.5/CU -> 20%
// tail from the 3-vs-2 block imbalance). Thread = (jq = t&3, b = (t>>2)&15,
// nl = t>>6) computing 4 consecutive rows x 8 hidden units -> h[4][8];
// 4 rows/thread keeps round-4's W1-amortization (128 b128 serve 4 rows).
//
// Session journal:
//  * jq in lane bits 0-1: quarter-dot reduction = shfl_xor(1)/(2) DPP
//    quad_perm (pure VALU). Reduction order (q0+q1)+(q2+q3) preserved.
//  * round-2 post-mortem: NEVER fuse the final reduction via __threadfence
//    — it is a whole-L2 writeback/inv on gfx950 (cost +50 µs).
// ---------------------------------------------------------------------------
__global__ __launch_bounds__(128, 2) void k_weights(
    const float* __restrict__ data,   // [B][NVEC][NDIM]
    const float* __restrict__ fW1,    // [NW][NDIM][NHID]
    const float* __restrict__ fb1,    // [NW][NHID]
    const float* __restrict__ fW2,    // [NW][NHID][NVEC]
    const float* __restrict__ fb2,    // [NW][NVEC]
    float* __restrict__ Wsp)          // [NW][B][NVEC][WPAD]
{
    const int i = blockIdx.y;
    const int nbase = blockIdx.x * NROW;
    const int t = threadIdx.x;        // 0..127
    const int jq = t & 3;
    const int b  = (t >> 2) & 15;
    const int nl = t >> 6;            // wave index 0..1 (4 rows each)
    const int j0 = jq * 8;

    __shared__ __align__(16) float sW1[NDIM * NHID];        // [d][j], 8 KB
    __shared__ float sb1[NHID];
    __shared__ __align__(16) float sW2r[NSLOT * W2PAD];     // 9.2 KB
    __shared__ float sb2[NSLOT];                            // fb2 at slots
    __shared__ __align__(16) float rws[NROW * BATCH * WPAD];// 6 KB

    {
        const float4* w1v = (const float4*)(fW1 + (size_t)i * NDIM * NHID);
        float4* s4 = (float4*)sW1;
        #pragma unroll
        for (int k = t; k < NDIM * NHID / 4; k += 128) s4[k] = w1v[k];
        if (t < NHID) sb1[t] = fb1[i * NHID + t];

        // stage the 64 needed fW2 columns (rows of W2^T) into LDS.
        // lane = slot (s fast) so each wave's 64 loads hit contiguous m
        // segments (24 contiguous + 5 groups of 8).
        const int s  = t & 63;
        const int j2 = t >> 6;        // 0..1
        int k = (s < 24) ? s : ((32 << ((s - 24) >> 3)) + ((s - 24) & 7));
        int m = (nbase + k) & (NVEC - 1);
        const float* w2 = fW2 + (size_t)i * NHID * NVEC + m;
        #pragma unroll
        for (int jj = 0; jj < 16; ++jj)
            sW2r[s * W2PAD + (j2 + jj * 2)] = w2[(size_t)(j2 + jj * 2) * NVEC];
        if (t < NSLOT) sb2[s] = fb2[(size_t)i * NVEC + m];

        // zero the WPAD pad slot so Wsp never carries stale-LDS bits
        rws[t * WPAD + (WPAD - 1)] = 0.0f;
    }
    __syncthreads();

    float h[4][8];
    #pragma unroll
    for (int r = 0; r < 4; ++r)
        #pragma unroll
        for (int jj = 0; jj < 8; ++jj) h[r][jj] = sb1[j0 + jj];

    const int n0 = nbase + nl * 4;    // 4 consecutive rows -> one base ptr
    const float4* rowp = (const float4*)(data + ((size_t)(b * NVEC) + n0) * NDIM);

    #pragma unroll 2
    for (int g = 0; g < 16; ++g) {    // 4 d-dims per iteration
        float4 a0 = rowp[g];
        float4 a1 = rowp[16 + g];
        float4 a2 = rowp[32 + g];
        float4 a3 = rowp[48 + g];
        const float as[4][4] = {{a0.x, a0.y, a0.z, a0.w},
                                {a1.x, a1.y, a1.z, a1.w},
                                {a2.x, a2.y, a2.z, a2.w},
                                {a3.x, a3.y, a3.z, a3.w}};
        #pragma unroll
        for (int dk = 0; dk < 4; ++dk) {
            const float4* wp = (const float4*)(&sW1[(g * 4 + dk) * NHID + j0]);
            float4 w0 = wp[0], w1 = wp[1];
            const float wf[8] = {w0.x, w0.y, w0.z, w0.w, w1.x, w1.y, w1.z, w1.w};
            #pragma unroll
            for (int jj = 0; jj < 8; ++jj) {
                h[0][jj] += as[0][dk] * wf[jj];
                h[1][jj] += as[1][dk] * wf[jj];
                h[2][jj] += as[2][dk] * wf[jj];
                h[3][jj] += as[3][dk] * wf[jj];
            }
        }
    }

    // exact gelu (bit-match with reference)
    #pragma unroll
    for (int r = 0; r < 4; ++r)
        #pragma unroll
        for (int jj = 0; jj < 8; ++jj) {
            float x = h[r][jj];
            h[r][jj] = 0.5f * x * (1.0f + erff(x * 0.70710678118654752f));
        }

    // sparse gather: W[n, (n+off)&1023] = h[n] . W2T[(n+off)&1023] + b2
    const int rbase = nl * 4;         // 0 or 4
    #pragma unroll
    for (int r = 0; r < 4; ++r) {
        #pragma unroll
        for (int o = 0; o < NOFF; ++o) {
            int slot;
            if (o == 0) slot = rbase + r;
            else {
                int off = 1 << (o - 1);
                slot = (off <= 16) ? (rbase + r + off)
                                   : (24 + 8 * (o - 6) + rbase + r);
            }
            const float4* gp = (const float4*)(sW2r + slot * W2PAD + j0);
            float4 g0 = gp[0], g1 = gp[1];
            float w = h[r][0] * g0.x + h[r][1] * g0.y + h[r][2] * g0.z + h[r][3] * g0.w
                    + h[r][4] * g1.x + h[r][5] * g1.y + h[r][6] * g1.z + h[r][7] * g1.w;
            w += __shfl_xor(w, 1, 64);    // combine jq bit 0 (DPP quad_perm)
            w += __shfl_xor(w, 2, 64);    // combine jq bit 1 (DPP quad_perm)
            if (jq == (o & 3))
                rws[(b * NROW + rbase + r) * WPAD + o] = w + sb2[slot];
        }
    }
    __syncthreads();

    // coalesced write-out: 128 rows x 12 floats = 384 float4
    {
        const float4* rv = (const float4*)rws;
        #pragma unroll
        for (int k = t; k < NROW * BATCH * 3; k += 128) {
            int row = k / 3, comp = k - row * 3;
            int bb = row >> 3, rr = row & 7;
            float4* dst = (float4*)(Wsp +
                ((size_t)(i * BATCH + bb) * NVEC + nbase + rr) * WPAD + comp * 4);
            *dst = rv[k];
        }
    }
}

// ---------------------------------------------------------------------------
// Kernel 2: FUSED 10-layer chain + final-projection partials.
// Block = (b, 4-dim chunk): V[1024][4] slice in LDS. 512 threads; thread n
// owns rows n AND n+512 in registers -> the offset-512 gather is a REGISTER
// read for both rows ((n+512)+512 wraps to n): 18 LDS reads + 2 writes per
// thread per layer vs 22 for two 1-row threads, and barrier width halves.
// Grid stays 256 -> one block per CU. Cross-wave reduction re-mapped so
// sred[w] (w=0..15) holds bitwise the same 16 partials as the 16-wave
// version -> output bit-identical.
// XCD-aware mapping: all 16 chunk-blocks of a b land on one XCD (L2 reuse
// of the per-layer 48 KB Wsp slab).
// grid (256), block 512.
// ---------------------------------------------------------------------------
__global__ __launch_bounds__(512) void k_chain(
    const float* __restrict__ data,   // [B][NVEC][NDIM]
    const float* __restrict__ Wsp,    // [NW][B][NVEC][WPAD]
    const float* __restrict__ Wf,     // [NVEC*NDIM][NCLS]
    float* __restrict__ part)         // [B][NCHUNK][NCLS]
{
    const int lin   = blockIdx.x;
    const int xcd   = lin & 7;
    const int slot  = lin >> 3;             // 0..31
    const int b     = (xcd << 1) | (slot >> 4);
    const int chunk = slot & 15;
    const int d0    = chunk * 4;
    const int n     = threadIdx.x;          // 0..511
    const int n2    = n + 512;

    __shared__ float4 bufA[NVEC];
    __shared__ float4 bufB[NVEC];

    float4 v0own = *(const float4*)(data + ((size_t)(b * NVEC) + n)  * NDIM + d0);
    float4 v1own = *(const float4*)(data + ((size_t)(b * NVEC) + n2) * NDIM + d0);
    bufA[n]  = v0own;
    bufA[n2] = v1own;

    // prefetch layer NW-1 weights for both rows
    const float* wbase = Wsp + (size_t)((NW - 1) * BATCH + b) * NVEC * WPAD;
    const float4* wp0 = (const float4*)(wbase + (size_t)n  * WPAD);
    const float4* wp1 = (const float4*)(wbase + (size_t)n2 * WPAD);
    float4 wa0 = wp0[0], wb0 = wp0[1], wc0 = wp0[2];
    float4 wa1 = wp1[0], wb1 = wp1[1], wc1 = wp1[2];
    __syncthreads();

    float4* cur = bufA;
    float4* nxt = bufB;

    for (int l = 0; l < NW; ++l) {
        float4 na0, nb0, nc0, na1, nb1, nc1;
        if (l < NW - 1) {   // prefetch next layer (in flight across barrier)
            const float* nbase_p = Wsp + (size_t)((NW - 2 - l) * BATCH + b) * NVEC * WPAD;
            const float4* q0 = (const float4*)(nbase_p + (size_t)n  * WPAD);
            const float4* q1 = (const float4*)(nbase_p + (size_t)n2 * WPAD);
            na0 = q0[0]; nb0 = q0[1]; nc0 = q0[2];
            na1 = q1[0]; nb1 = q1[1]; nc1 = q1[2];
        }
        const float wg0[12] = {wa0.x, wa0.y, wa0.z, wa0.w,
                               wb0.x, wb0.y, wb0.z, wb0.w,
                               wc0.x, wc0.y, wc0.z, wc0.w};
        const float wg1[12] = {wa1.x, wa1.y, wa1.z, wa1.w,
                               wb1.x, wb1.y, wb1.z, wb1.w,
                               wc1.x, wc1.y, wc1.z, wc1.w};
        // row n (diag + offsets; offset 512 comes from v1own register)
        float4 acc0;
        acc0.x = v0own.x + wg0[0] * v0own.x;
        acc0.y = v0own.y + wg0[0] * v0own.y;
        acc0.z = v0own.z + wg0[0] * v0own.z;
        acc0.w = v0own.w + wg0[0] * v0own.w;
        #pragma unroll
        for (int o = 1; o < NOFF; ++o) {
            int off = 1 << (o - 1);
            float4 vv = (off == 512) ? v1own : cur[(n + off) & (NVEC - 1)];
            acc0.x += wg0[o] * vv.x; acc0.y += wg0[o] * vv.y;
            acc0.z += wg0[o] * vv.z; acc0.w += wg0[o] * vv.w;
        }
        // row n+512 (offset 512 wraps to row n -> v0own register)
        float4 acc1;
        acc1.x = v1own.x + wg1[0] * v1own.x;
        acc1.y = v1own.y + wg1[0] * v1own.y;
        acc1.z = v1own.z + wg1[0] * v1own.z;
        acc1.w = v1own.w + wg1[0] * v1own.w;
        #pragma unroll
        for (int o = 1; o < NOFF; ++o) {
            int off = 1 << (o - 1);
            float4 vv = (off == 512) ? v0own : cur[(n2 + off) & (NVEC - 1)];
            acc1.x += wg1[o] * vv.x; acc1.y += wg1[o] * vv.y;
            acc1.z += wg1[o] * vv.z; acc1.w += wg1[o] * vv.w;
        }
        nxt[n]  = acc0;
        nxt[n2] = acc1;
        v0own = acc0;
        v1own = acc1;
        __syncthreads();
        float4* tmp = cur; cur = nxt; nxt = tmp;
        if (l < NW - 1) {
            wa0 = na0; wb0 = nb0; wc0 = nc0;
            wa1 = na1; wb1 = nb1; wc1 = nc1;
        }
    }

    // fused final projection partials for both rows — from registers
    float p0[NCLS], p1[NCLS];
    #pragma unroll
    for (int c = 0; c < NCLS; ++c) { p0[c] = 0.0f; p1[c] = 0.0f; }
    {
        float vs0[4] = {v0own.x, v0own.y, v0own.z, v0own.w};
        float vs1[4] = {v1own.x, v1own.y, v1own.z, v1own.w};
        const float4* wfv0 = (const float4*)(Wf + ((size_t)(n  * NDIM + d0)) * NCLS);
        const float4* wfv1 = (const float4*)(Wf + ((size_t)(n2 * NDIM + d0)) * NCLS);
        float wf0[40], wf1[40];
        #pragma unroll
        for (int k = 0; k < 10; ++k) {
            float4 u0 = wfv0[k], u1 = wfv1[k];
            wf0[k * 4 + 0] = u0.x; wf0[k * 4 + 1] = u0.y;
            wf0[k * 4 + 2] = u0.z; wf0[k * 4 + 3] = u0.w;
            wf1[k * 4 + 0] = u1.x; wf1[k * 4 + 1] = u1.y;
            wf1[k * 4 + 2] = u1.z; wf1[k * 4 + 3] = u1.w;
        }
        #pragma unroll
        for (int d = 0; d < 4; ++d)
            #pragma unroll
            for (int cls = 0; cls < NCLS; ++cls) {
                p0[cls] += vs0[d] * wf0[d * NCLS + cls];
                p1[cls] += vs1[d] * wf1[d * NCLS + cls];
            }
    }

    // reduce -> 10 values. Wave wv (0..7) produces the partials the old
    // 16-wave version's waves wv (rows wv*64..) and wv+8 (rows 512+wv*64..)
    // produced: identical lane->row mapping, identical shfl tree, then
    // identical w=0..15 ascending sum -> bitwise-equal result.
    const int lane = n & 63, wv = n >> 6;   // 8 waves
    float* sred = (float*)nxt;              // dead buffer
    #pragma unroll
    for (int cls = 0; cls < NCLS; ++cls) {
        float v0 = p0[cls];
        float v1 = p1[cls];
        #pragma unroll
        for (int s = 32; s > 0; s >>= 1) {
            v0 += __shfl_down(v0, s, 64);
            v1 += __shfl_down(v1, s, 64);
        }
        if (lane == 0) {
            sred[wv * NCLS + cls]       = v0;
            sred[(wv + 8) * NCLS + cls] = v1;
        }
    }
    __syncthreads();
    if (n < NCLS) {
        float s = 0.0f;
        #pragma unroll
        for (int w = 0; w < 16; ++w) s += sred[w * NCLS + n];
        part[(size_t)(b * NCHUNK + chunk) * NCLS + n] = s;
    }
}

// ---------------------------------------------------------------------------
__global__ __launch_bounds__(256) void k_finish(
    const float* __restrict__ part, const float* __restrict__ bias,
    float* __restrict__ out)
{
    int t = threadIdx.x;
    if (t < BATCH * NCLS) {
        int b = t / NCLS, cls = t % NCLS;
        float s = bias[cls];
        #pragma unroll
        for (int ch = 0; ch < NCHUNK; ++ch)
            s += part[(size_t)(b * NCHUNK + ch) * NCLS + cls];
        out[t] = s;
    }
}

// ---------------------------------------------------------------------------
extern "C" void kernel_launch(void* const* d_in, const int* in_sizes, int n_in,
                              void* d_out, int out_size, void* d_ws, size_t ws_size,
                              hipStream_t stream) {
    const float* data = (const float*)d_in[0];
    const float* fW1  = (const float*)d_in[1];
    const float* fb1  = (const float*)d_in[2];
    const float* fW2  = (const float*)d_in[3];
    const float* fb2  = (const float*)d_in[4];
    const float* fWf  = (const float*)d_in[5];
    const float* fbf  = (const float*)d_in[6];
    float* out = (float*)d_out;

    float* ws   = (float*)d_ws;
    float* Wsp  = ws;                                         // NW*B*NVEC*WPAD = 1,966,080 f
    float* part = Wsp + (size_t)NW * BATCH * NVEC * WPAD;     // B*NCHUNK*NCLS = 2,560 f

    k_weights<<<dim3(NVEC / NROW, NW), 128, 0, stream>>>(
        data, fW1, fb1, fW2, fb2, Wsp);
    k_chain<<<dim3(NCHUNK * BATCH), 512, 0, stream>>>(data, Wsp, fWf, part);
    k_finish<<<dim3(1), 256, 0, stream>>>(part, fbf, out);
}